// Round 1
// baseline (2324.610 us; speedup 1.0000x reference)
//
#include <hip/hip_runtime.h>
#include <cstdint>

// ---------------------------------------------------------------------------
// JukeboxAutoEncoder: fp32 implementation.
// Layout: all activations (B, T, C=64), C contiguous.
// Output layout (flat f32): x_hat[262144] | loss_vq[1] | ids[32768] | sim[16777216]
// ---------------------------------------------------------------------------

#define OFF_LOSS 262144
#define OFF_IDS  262145
#define OFF_SIM  294913

// ---------------- down0: (B,65536,1) -> (B,32768,64), K=4 stride2, relu ----
__global__ __launch_bounds__(256) void down0_kernel(
    const float* __restrict__ x, const float* __restrict__ w,
    const float* __restrict__ bias, float* __restrict__ y)
{
  int idx = blockIdx.x * 256 + threadIdx.x;   // enumerates (b, t, co)
  int co = idx & 63;
  int r  = idx >> 6;
  int t  = r & 32767;
  int b  = r >> 15;
  const float* xb = x + (size_t)b * 65536;
  float acc = bias[co];
  #pragma unroll
  for (int k = 0; k < 4; ++k) {
    int gt = 2 * t - 1 + k;
    float xv = ((unsigned)gt < 65536u) ? xb[gt] : 0.f;
    acc += xv * w[k * 64 + co];
  }
  y[(size_t)idx] = fmaxf(acc, 0.f);
}

// ---------------- conv3: K=3, dilation DIL, 64->64, relu, optional +res ----
// y = (HAS_RES ? res : 0) + relu(conv(x) + bias)
template <int DIL, bool HAS_RES>
__global__ __launch_bounds__(256) void conv3_kernel(
    const float* __restrict__ x, const float* __restrict__ w,
    const float* __restrict__ bias, const float* res,
    float* y, int T)
{
  constexpr int XT = 64 + 2 * DIL;
  constexpr int XS = XT + 1;                 // odd stride -> conflict-free
  __shared__ float xs[64 * XS];
  __shared__ float wsm[4096];                // one k-slice: 64x64
  const int tid = threadIdx.x;
  const int b   = blockIdx.y;
  const int t0  = blockIdx.x * 64;

  for (int e = tid; e < 64 * XT; e += 256) { // transpose to [ci][t]
    int tl = e >> 6, ci = e & 63;
    int gt = t0 - DIL + tl;
    float v = 0.f;
    if ((unsigned)gt < (unsigned)T) v = x[((size_t)b * T + gt) * 64 + ci];
    xs[ci * XS + tl] = v;
  }

  const int co = (tid & 15) * 4;
  const int tb = (tid >> 4) * 4;
  float acc[4][4] = {};

  for (int k = 0; k < 3; ++k) {
    __syncthreads();
    {
      const float4* src = (const float4*)(w + (size_t)k * 4096);
      float4* dst = (float4*)wsm;
      for (int i = tid; i < 1024; i += 256) dst[i] = src[i];
    }
    __syncthreads();
    const float* xk = xs + tb + k * DIL;
    #pragma unroll 8
    for (int ci = 0; ci < 64; ++ci) {
      float4 wv = *(const float4*)&wsm[ci * 64 + co];
      float x0 = xk[ci * XS + 0];
      float x1 = xk[ci * XS + 1];
      float x2 = xk[ci * XS + 2];
      float x3 = xk[ci * XS + 3];
      acc[0][0] += x0 * wv.x; acc[0][1] += x0 * wv.y; acc[0][2] += x0 * wv.z; acc[0][3] += x0 * wv.w;
      acc[1][0] += x1 * wv.x; acc[1][1] += x1 * wv.y; acc[1][2] += x1 * wv.z; acc[1][3] += x1 * wv.w;
      acc[2][0] += x2 * wv.x; acc[2][1] += x2 * wv.y; acc[2][2] += x2 * wv.z; acc[2][3] += x2 * wv.w;
      acc[3][0] += x3 * wv.x; acc[3][1] += x3 * wv.y; acc[3][2] += x3 * wv.z; acc[3][3] += x3 * wv.w;
    }
  }

  float4 bv = *(const float4*)&bias[co];
  #pragma unroll
  for (int i = 0; i < 4; ++i) {
    size_t o = ((size_t)b * T + t0 + tb + i) * 64 + co;
    float4 rr;
    rr.x = fmaxf(acc[i][0] + bv.x, 0.f);
    rr.y = fmaxf(acc[i][1] + bv.y, 0.f);
    rr.z = fmaxf(acc[i][2] + bv.z, 0.f);
    rr.w = fmaxf(acc[i][3] + bv.w, 0.f);
    if (HAS_RES) {
      float4 rv = *(const float4*)&res[o];
      rr.x += rv.x; rr.y += rv.y; rr.z += rv.z; rr.w += rv.w;
    }
    *(float4*)&y[o] = rr;
  }
}

// ---------------- down2: K=4 stride2, 64->64, relu ------------------------
__global__ __launch_bounds__(256) void down2_kernel(
    const float* __restrict__ x, const float* __restrict__ w,
    const float* __restrict__ bias, float* __restrict__ y, int Tin)
{
  constexpr int XT = 130, XS = 131;
  __shared__ float xs[64 * XS];
  __shared__ float wsm[4096];
  const int tid = threadIdx.x;
  const int b   = blockIdx.y;
  const int t0  = blockIdx.x * 64;
  const int Tout = Tin >> 1;

  for (int e = tid; e < 64 * XT; e += 256) {
    int tl = e >> 6, ci = e & 63;
    int gt = 2 * t0 - 1 + tl;
    float v = 0.f;
    if ((unsigned)gt < (unsigned)Tin) v = x[((size_t)b * Tin + gt) * 64 + ci];
    xs[ci * XS + tl] = v;
  }

  const int co = (tid & 15) * 4;
  const int tb = (tid >> 4) * 4;
  float acc[4][4] = {};

  for (int k = 0; k < 4; ++k) {
    __syncthreads();
    {
      const float4* src = (const float4*)(w + (size_t)k * 4096);
      float4* dst = (float4*)wsm;
      for (int i = tid; i < 1024; i += 256) dst[i] = src[i];
    }
    __syncthreads();
    const float* xk = xs + 2 * tb + k;
    #pragma unroll 8
    for (int ci = 0; ci < 64; ++ci) {
      float4 wv = *(const float4*)&wsm[ci * 64 + co];
      float x0 = xk[ci * XS + 0];
      float x1 = xk[ci * XS + 2];
      float x2 = xk[ci * XS + 4];
      float x3 = xk[ci * XS + 6];
      acc[0][0] += x0 * wv.x; acc[0][1] += x0 * wv.y; acc[0][2] += x0 * wv.z; acc[0][3] += x0 * wv.w;
      acc[1][0] += x1 * wv.x; acc[1][1] += x1 * wv.y; acc[1][2] += x1 * wv.z; acc[1][3] += x1 * wv.w;
      acc[2][0] += x2 * wv.x; acc[2][1] += x2 * wv.y; acc[2][2] += x2 * wv.z; acc[2][3] += x2 * wv.w;
      acc[3][0] += x3 * wv.x; acc[3][1] += x3 * wv.y; acc[3][2] += x3 * wv.z; acc[3][3] += x3 * wv.w;
    }
  }

  float4 bv = *(const float4*)&bias[co];
  #pragma unroll
  for (int i = 0; i < 4; ++i) {
    size_t o = ((size_t)b * Tout + t0 + tb + i) * 64 + co;
    float4 rr;
    rr.x = fmaxf(acc[i][0] + bv.x, 0.f);
    rr.y = fmaxf(acc[i][1] + bv.y, 0.f);
    rr.z = fmaxf(acc[i][2] + bv.z, 0.f);
    rr.w = fmaxf(acc[i][3] + bv.w, 0.f);
    *(float4*)&y[o] = rr;
  }
}

// ---------------- up: conv_transpose K=4 stride2, 64->64, relu ------------
// y[2u]   = relu(b + w0^T x[u-1] + w2^T x[u])
// y[2u+1] = relu(b + w1^T x[u]   + w3^T x[u+1])
__global__ __launch_bounds__(256) void up_kernel(
    const float* __restrict__ x, const float* __restrict__ w,
    const float* __restrict__ bias, float* __restrict__ y, int Tin)
{
  constexpr int XT = 34, XS = 35;
  __shared__ float xs[64 * XS];
  __shared__ float wsm[4096];
  const int tid = threadIdx.x;
  const int b   = blockIdx.y;
  const int t0  = blockIdx.x * 64;
  const int u0  = t0 >> 1;
  const int Tout = Tin << 1;

  for (int e = tid; e < 64 * XT; e += 256) {
    int ul = e >> 6, ci = e & 63;
    int gu = u0 - 1 + ul;
    float v = 0.f;
    if ((unsigned)gu < (unsigned)Tin) v = x[((size_t)b * Tin + gu) * 64 + ci];
    xs[ci * XS + ul] = v;
  }

  const int co = (tid & 15) * 4;
  const int tb = (tid >> 4) * 4;
  const int ub = tb >> 1;
  float acc[4][4] = {};

  #pragma unroll
  for (int k = 0; k < 4; ++k) {
    __syncthreads();
    {
      const float4* src = (const float4*)(w + (size_t)k * 4096);
      float4* dst = (float4*)wsm;
      for (int i = tid; i < 1024; i += 256) dst[i] = src[i];
    }
    __syncthreads();
    const int base = (k + 1) >> 1;  // 0,1,1,2
    const int p = k & 1;            // parity row
    #pragma unroll 8
    for (int ci = 0; ci < 64; ++ci) {
      float4 wv = *(const float4*)&wsm[ci * 64 + co];
      float xa = xs[ci * XS + ub + base];
      float xb2 = xs[ci * XS + ub + base + 1];
      acc[p][0]   += xa * wv.x;  acc[p][1]   += xa * wv.y;  acc[p][2]   += xa * wv.z;  acc[p][3]   += xa * wv.w;
      acc[p+2][0] += xb2 * wv.x; acc[p+2][1] += xb2 * wv.y; acc[p+2][2] += xb2 * wv.z; acc[p+2][3] += xb2 * wv.w;
    }
  }

  float4 bv = *(const float4*)&bias[co];
  #pragma unroll
  for (int i = 0; i < 4; ++i) {
    size_t o = ((size_t)b * Tout + t0 + tb + i) * 64 + co;
    float4 rr;
    rr.x = fmaxf(acc[i][0] + bv.x, 0.f);
    rr.y = fmaxf(acc[i][1] + bv.y, 0.f);
    rr.z = fmaxf(acc[i][2] + bv.z, 0.f);
    rr.w = fmaxf(acc[i][3] + bv.w, 0.f);
    *(float4*)&y[o] = rr;
  }
}

// ---------------- proj: K=3 dil1, 64->1, linear ---------------------------
__global__ __launch_bounds__(256) void proj_kernel(
    const float* __restrict__ x, const float* __restrict__ w,
    const float* __restrict__ bias, float* __restrict__ out)
{
  const int lane = threadIdx.x & 63;
  const int wid  = (blockIdx.x * 256 + threadIdx.x) >> 6;  // 4096 waves
  const float w0 = w[lane], w1 = w[64 + lane], w2 = w[128 + lane];
  const float bb = bias[0];
  size_t base = (size_t)wid * 64;
  for (int i = 0; i < 64; ++i) {
    size_t tau = base + i;
    int b = (int)(tau >> 16);
    int t = (int)(tau & 65535);
    const float* xb = x + ((size_t)b * 65536) * 64;
    float pm = (t > 0)     ? xb[(size_t)(t - 1) * 64 + lane] : 0.f;
    float pc =               xb[(size_t)t * 64 + lane];
    float pp = (t < 65535) ? xb[(size_t)(t + 1) * 64 + lane] : 0.f;
    float s = pm * w0 + pc * w1 + pp * w2;
    #pragma unroll
    for (int off = 32; off; off >>= 1) s += __shfl_down(s, off);
    if (lane == 0) out[tau] = s + bb;
  }
}

// ---------------- nz: per-token sum of squares ----------------------------
__global__ __launch_bounds__(256) void nz_kernel(
    const float* __restrict__ ze, float* __restrict__ nz)
{
  int lane = threadIdx.x & 63;
  int tok  = (blockIdx.x * 256 + threadIdx.x) >> 6;  // 32768 waves
  float v = ze[(size_t)tok * 64 + lane];
  float s = v * v;
  #pragma unroll
  for (int off = 32; off; off >>= 1) s += __shfl_down(s, off);
  if (lane == 0) nz[tok] = s;
}

// ---------------- VQ: argmin, z_q, ids, similarity, loss ------------------
#define VQ_TOKS 16
__global__ __launch_bounds__(256) void vq_kernel(
    const float* __restrict__ ze, const float* __restrict__ cb,
    const float* __restrict__ nzbuf, float* __restrict__ zq,
    float* __restrict__ ids_out, float* __restrict__ sim_out,
    float* __restrict__ loss_acc)
{
  const int tid = threadIdx.x;
  const int c0 = tid, c1 = tid + 256;
  float r0[64], r1[64];
  #pragma unroll
  for (int q = 0; q < 16; ++q) {
    float4 a = ((const float4*)cb)[c0 * 16 + q];
    r0[4*q] = a.x; r0[4*q+1] = a.y; r0[4*q+2] = a.z; r0[4*q+3] = a.w;
    float4 bq = ((const float4*)cb)[c1 * 16 + q];
    r1[4*q] = bq.x; r1[4*q+1] = bq.y; r1[4*q+2] = bq.z; r1[4*q+3] = bq.w;
  }
  float ne0 = 0.f, ne1 = 0.f;
  #pragma unroll
  for (int d = 0; d < 64; ++d) { ne0 += r0[d] * r0[d]; ne1 += r1[d] * r1[d]; }
  const float sne0 = sqrtf(ne0), sne1 = sqrtf(ne1);

  __shared__ float wmin[4];
  __shared__ int   widx[4];
  __shared__ int   sbest;
  const int lane = tid & 63, wvid = tid >> 6;
  float lloss = 0.f;

  for (int it = 0; it < VQ_TOKS; ++it) {
    const int tok = blockIdx.x * VQ_TOKS + it;
    const float4* z4 = (const float4*)(ze + (size_t)tok * 64);
    float dot0 = 0.f, dot1 = 0.f;
    #pragma unroll
    for (int q = 0; q < 16; ++q) {
      float4 zv = z4[q];
      dot0 += zv.x * r0[4*q] + zv.y * r0[4*q+1] + zv.z * r0[4*q+2] + zv.w * r0[4*q+3];
      dot1 += zv.x * r1[4*q] + zv.y * r1[4*q+1] + zv.z * r1[4*q+2] + zv.w * r1[4*q+3];
    }
    const float nzv = nzbuf[tok];
    const float snz = sqrtf(nzv);
    float dist0 = (-2.f * dot0 + nzv) + ne0;
    float dist1 = (-2.f * dot1 + nzv) + ne1;

    float* simrow = sim_out + (size_t)tok * 512;
    simrow[c0] = dot0 / snz / sne0;
    simrow[c1] = dot1 / snz / sne1;

    float md; int mi;
    if (dist1 < dist0) { md = dist1; mi = c1; } else { md = dist0; mi = c0; }
    #pragma unroll
    for (int off = 32; off; off >>= 1) {
      float od = __shfl_down(md, off);
      int   oi = __shfl_down(mi, off);
      if (od < md || (od == md && oi < mi)) { md = od; mi = oi; }
    }
    if (lane == 0) { wmin[wvid] = md; widx[wvid] = mi; }
    __syncthreads();
    if (tid == 0) {
      float bm = wmin[0]; int bi = widx[0];
      #pragma unroll
      for (int wq = 1; wq < 4; ++wq) {
        float om = wmin[wq]; int oi = widx[wq];
        if (om < bm || (om == bm && oi < bi)) { bm = om; bi = oi; }
      }
      sbest = bi;
      ids_out[tok] = (float)bi;
    }
    __syncthreads();
    const int best = sbest;
    if (best == c0) {
      float s = 0.f;
      float4* zqr = (float4*)(zq + (size_t)tok * 64);
      #pragma unroll
      for (int q = 0; q < 16; ++q) {
        float4 zv = z4[q];
        float dx = zv.x - r0[4*q], dy = zv.y - r0[4*q+1];
        float dz2 = zv.z - r0[4*q+2], dw = zv.w - r0[4*q+3];
        s += dx*dx + dy*dy + dz2*dz2 + dw*dw;
        zqr[q] = make_float4(r0[4*q], r0[4*q+1], r0[4*q+2], r0[4*q+3]);
      }
      lloss += sqrtf(s);
    } else if (best == c1) {
      float s = 0.f;
      float4* zqr = (float4*)(zq + (size_t)tok * 64);
      #pragma unroll
      for (int q = 0; q < 16; ++q) {
        float4 zv = z4[q];
        float dx = zv.x - r1[4*q], dy = zv.y - r1[4*q+1];
        float dz2 = zv.z - r1[4*q+2], dw = zv.w - r1[4*q+3];
        s += dx*dx + dy*dy + dz2*dz2 + dw*dw;
        zqr[q] = make_float4(r1[4*q], r1[4*q+1], r1[4*q+2], r1[4*q+3]);
      }
      lloss += sqrtf(s);
    }
  }

  float s = lloss;
  #pragma unroll
  for (int off = 32; off; off >>= 1) s += __shfl_down(s, off);
  __shared__ float lsum[4];
  if (lane == 0) lsum[wvid] = s;
  __syncthreads();
  if (tid == 0) atomicAdd(loss_acc, lsum[0] + lsum[1] + lsum[2] + lsum[3]);
}

__global__ void loss_fin_kernel(const float* __restrict__ loss_acc,
                                float* __restrict__ out)
{
  out[0] = 1.25f * loss_acc[0] / 32768.f;
}

// ---------------------------------------------------------------------------
extern "C" void kernel_launch(void* const* d_in, const int* in_sizes, int n_in,
                              void* d_out, int out_size, void* d_ws, size_t ws_size,
                              hipStream_t stream)
{
  const float* x       = (const float*)d_in[0];
  const float* w_down0 = (const float*)d_in[1];
  const float* b_down0 = (const float*)d_in[2];
  const float* w_down  = (const float*)d_in[3];
  const float* b_down  = (const float*)d_in[4];
  const float* w_res_e = (const float*)d_in[5];
  const float* b_res_e = (const float*)d_in[6];
  const float* cb      = (const float*)d_in[7];
  const float* w_res_d = (const float*)d_in[8];
  const float* b_res_d = (const float*)d_in[9];
  const float* w_up    = (const float*)d_in[10];
  const float* b_up    = (const float*)d_in[11];
  const float* w_proj  = (const float*)d_in[12];
  const float* b_proj  = (const float*)d_in[13];

  float* out = (float*)d_out;
  const size_t BUF = (size_t)4 * 65536 * 64;
  float* bufA     = (float*)d_ws;
  float* bufB     = bufA + BUF;
  float* nzbuf    = bufB + BUF;
  float* loss_acc = nzbuf + 32768;

  float* h = bufA;
  float* tmp = bufB;

  // ---- encoder ----
  down0_kernel<<<32768, 256, 0, stream>>>(x, w_down0, b_down0, h);
  int T = 32768;
  for (int blk = 0; blk < 3; ++blk) {
    if (blk > 0) {
      down2_kernel<<<dim3(T / 2 / 64, 4), 256, 0, stream>>>(
          h, w_down + (size_t)(blk - 1) * 4 * 64 * 64, b_down + (blk - 1) * 64, tmp, T);
      T >>= 1;
      float* s = h; h = tmp; tmp = s;
    }
    for (int r = 0; r < 4; ++r) {
      const float* w0p = w_res_e + (((size_t)blk * 4 + r) * 2 + 0) * 3 * 64 * 64;
      const float* w1p = w_res_e + (((size_t)blk * 4 + r) * 2 + 1) * 3 * 64 * 64;
      const float* b0p = b_res_e + (((size_t)blk * 4 + r) * 2 + 0) * 64;
      const float* b1p = b_res_e + (((size_t)blk * 4 + r) * 2 + 1) * 64;
      conv3_kernel<3, false><<<dim3(T / 64, 4), 256, 0, stream>>>(h, w0p, b0p, nullptr, tmp, T);
      conv3_kernel<1, true ><<<dim3(T / 64, 4), 256, 0, stream>>>(tmp, w1p, b1p, h, h, T);
    }
  }

  // ---- VQ (T == 8192, z_e in h) ----
  nz_kernel<<<8192, 256, 0, stream>>>(h, nzbuf);
  hipMemsetAsync(loss_acc, 0, sizeof(float), stream);
  vq_kernel<<<2048, 256, 0, stream>>>(h, cb, nzbuf, tmp, out + OFF_IDS, out + OFF_SIM, loss_acc);
  loss_fin_kernel<<<1, 1, 0, stream>>>(loss_acc, out + OFF_LOSS);
  { float* s = h; h = tmp; tmp = s; }  // h = z_q

  // ---- decoder ----
  for (int blk = 0; blk < 3; ++blk) {
    for (int r = 0; r < 4; ++r) {
      const float* w0p = w_res_d + (((size_t)blk * 4 + r) * 2 + 0) * 3 * 64 * 64;
      const float* w1p = w_res_d + (((size_t)blk * 4 + r) * 2 + 1) * 3 * 64 * 64;
      const float* b0p = b_res_d + (((size_t)blk * 4 + r) * 2 + 0) * 64;
      const float* b1p = b_res_d + (((size_t)blk * 4 + r) * 2 + 1) * 64;
      conv3_kernel<1, false><<<dim3(T / 64, 4), 256, 0, stream>>>(h, w0p, b0p, nullptr, tmp, T);
      conv3_kernel<3, true ><<<dim3(T / 64, 4), 256, 0, stream>>>(tmp, w1p, b1p, h, h, T);
    }
    up_kernel<<<dim3(2 * T / 64, 4), 256, 0, stream>>>(
        h, w_up + (size_t)blk * 4 * 64 * 64, b_up + blk * 64, tmp, T);
    T <<= 1;
    float* s = h; h = tmp; tmp = s;
  }

  // ---- final projection (T == 65536) ----
  proj_kernel<<<1024, 256, 0, stream>>>(h, w_proj, b_proj, out);
}